// Round 1
// baseline (408.202 us; speedup 1.0000x reference)
//
#include <hip/hip_runtime.h>
#include <math.h>

#define VOCAB  100000
#define DIM    300
#define BB     4096
#define LL     200
#define HIDDEN 1000
#define OUTC   3
#define TM     8        // batch rows per block

__device__ inline float4 f4max(float4 a, float4 b) {
    return make_float4(fmaxf(a.x, b.x), fmaxf(a.y, b.y), fmaxf(a.z, b.z), fmaxf(a.w, b.w));
}
__device__ inline float4 f4add(float4 a, float4 b) {
    return make_float4(a.x + b.x, a.y + b.y, a.z + b.z, a.w + b.w);
}
__device__ inline float4 f4scale(float4 a, float s) {
    return make_float4(a.x * s, a.y * s, a.z * s, a.w * s);
}

__global__ __launch_bounds__(256, 2) void fused_dnn(
    const float* __restrict__ emb,
    const float* __restrict__ W1,
    const float* __restrict__ b1,
    const float* __restrict__ W2,
    const float* __restrict__ b2,
    const int*   __restrict__ x,
    const int*   __restrict__ lengths,
    float*       __restrict__ out)
{
    __shared__ int   xS[TM * LL];             // 6.4 KB
    __shared__ float repS[TM][2 * DIM];       // 19.2 KB
    __shared__ float hS[TM][HIDDEN];          // 32 KB
    __shared__ float red[4][TM][OUTC];        // 384 B

    const int tid  = threadIdx.x;
    const int lane = tid & 63;
    const int wave = tid >> 6;
    const int b0   = blockIdx.x * TM;

    // ---- Phase 0: stage indices for the 8 rows into LDS ----
    for (int i = tid; i < TM * LL; i += 256) xS[i] = x[b0 * LL + i];
    __syncthreads();

    // ---- Phase 1: gather + mean/max pool. Each wave handles 2 rows. ----
    // Row = 300 floats = 75 float4: one full-wave float4 load + 11-lane tail.
    for (int rr = 0; rr < 2; ++rr) {
        const int r   = wave * 2 + rr;               // 0..7
        const int len = lengths[b0 + r];             // >= 1
        const bool tail = (lane < 11);

        float4 s0 = make_float4(0.f, 0.f, 0.f, 0.f);
        float4 s1 = make_float4(0.f, 0.f, 0.f, 0.f);
        float4 m0 = make_float4(-INFINITY, -INFINITY, -INFINITY, -INFINITY);
        float4 m1 = m0;
        const float4 z4 = make_float4(0.f, 0.f, 0.f, 0.f);

        int t = 0;
        // real tokens: contribute to sum AND max
        #pragma unroll 2
        for (; t < len; ++t) {
            const int idx = xS[r * LL + t];
            const float4* row = (const float4*)(emb + (size_t)idx * DIM);
            float4 a  = row[lane];
            float4 bv = tail ? row[64 + lane] : z4;
            s0 = f4add(s0, a);
            s1 = f4add(s1, bv);
            m0 = f4max(m0, a);
            m1 = f4max(m1, bv);
        }
        // padding tokens: reference's mean still sums them
        #pragma unroll 2
        for (; t < LL; ++t) {
            const int idx = xS[r * LL + t];
            const float4* row = (const float4*)(emb + (size_t)idx * DIM);
            float4 a  = row[lane];
            float4 bv = tail ? row[64 + lane] : z4;
            s0 = f4add(s0, a);
            s1 = f4add(s1, bv);
        }

        const float inv = 1.0f / (float)len;
        float4* mrow = (float4*)&repS[r][0];     // mean part, dims 0..299
        float4* xrow = (float4*)&repS[r][DIM];   // max part, dims 300..599
        mrow[lane] = f4scale(s0, inv);
        xrow[lane] = m0;
        if (tail) {
            mrow[64 + lane] = f4scale(s1, inv);
            xrow[64 + lane] = m1;
        }
    }
    __syncthreads();

    // ---- Phase 2: h = relu(rep @ W1 + b1), tile of 8 rows x 1000 cols ----
    // Thread owns cols n0..n3 = tid + {0,256,512,768}; per k: 4 coalesced W1
    // loads + 8 broadcast LDS reads + 32 FMA (VALU-bound).
    {
        const int  n0 = tid, n1 = tid + 256, n2 = tid + 512;
        const bool has3 = (tid + 768 < HIDDEN);
        const int  n3 = has3 ? (tid + 768) : (HIDDEN - 1);   // clamped dup read

        float acc0[TM], acc1[TM], acc2[TM], acc3[TM];
        const float bb0 = b1[n0], bb1 = b1[n1], bb2 = b1[n2], bb3 = b1[n3];
        #pragma unroll
        for (int r = 0; r < TM; ++r) {
            acc0[r] = bb0; acc1[r] = bb1; acc2[r] = bb2; acc3[r] = bb3;
        }

        #pragma unroll 4
        for (int k = 0; k < 2 * DIM; ++k) {
            const float* wrow = W1 + (size_t)k * HIDDEN;
            const float w0 = wrow[n0];
            const float w1 = wrow[n1];
            const float w2v = wrow[n2];
            const float w3 = wrow[n3];
            #pragma unroll
            for (int r = 0; r < TM; ++r) {
                const float rv = repS[r][k];
                acc0[r] = fmaf(rv, w0,  acc0[r]);
                acc1[r] = fmaf(rv, w1,  acc1[r]);
                acc2[r] = fmaf(rv, w2v, acc2[r]);
                acc3[r] = fmaf(rv, w3,  acc3[r]);
            }
        }

        #pragma unroll
        for (int r = 0; r < TM; ++r) {
            hS[r][n0] = fmaxf(acc0[r], 0.f);
            hS[r][n1] = fmaxf(acc1[r], 0.f);
            hS[r][n2] = fmaxf(acc2[r], 0.f);
            if (has3) hS[r][n3] = fmaxf(acc3[r], 0.f);
        }
    }
    __syncthreads();

    // ---- Phase 3: out = h @ W2 + b2 (reduction over 1000 cols) ----
    {
        float po[TM][OUTC];
        #pragma unroll
        for (int r = 0; r < TM; ++r)
            #pragma unroll
            for (int j = 0; j < OUTC; ++j) po[r][j] = 0.f;

        for (int n = tid; n < HIDDEN; n += 256) {
            const float w20 = W2[n * 3 + 0];
            const float w21 = W2[n * 3 + 1];
            const float w22 = W2[n * 3 + 2];
            #pragma unroll
            for (int r = 0; r < TM; ++r) {
                const float hv = hS[r][n];
                po[r][0] = fmaf(hv, w20, po[r][0]);
                po[r][1] = fmaf(hv, w21, po[r][1]);
                po[r][2] = fmaf(hv, w22, po[r][2]);
            }
        }

        // wave shuffle reduce, then cross-wave combine in LDS
        #pragma unroll
        for (int r = 0; r < TM; ++r) {
            #pragma unroll
            for (int j = 0; j < OUTC; ++j) {
                float v = po[r][j];
                v += __shfl_xor(v, 1);
                v += __shfl_xor(v, 2);
                v += __shfl_xor(v, 4);
                v += __shfl_xor(v, 8);
                v += __shfl_xor(v, 16);
                v += __shfl_xor(v, 32);
                if (lane == 0) red[wave][r][j] = v;
            }
        }
        __syncthreads();

        if (tid < TM * OUTC) {
            const int r = tid / OUTC;
            const int j = tid % OUTC;
            const float s = red[0][r][j] + red[1][r][j] + red[2][r][j] + red[3][r][j] + b2[j];
            out[(size_t)(b0 + r) * OUTC + j] = s;
        }
    }
}

extern "C" void kernel_launch(void* const* d_in, const int* in_sizes, int n_in,
                              void* d_out, int out_size, void* d_ws, size_t ws_size,
                              hipStream_t stream) {
    const float* emb = (const float*)d_in[0];
    const float* W1  = (const float*)d_in[1];
    const float* b1  = (const float*)d_in[2];
    const float* W2  = (const float*)d_in[3];
    const float* b2  = (const float*)d_in[4];
    const int*   x   = (const int*)d_in[5];
    const int*   len = (const int*)d_in[6];
    float* out = (float*)d_out;

    dim3 grid(BB / TM);   // 512 blocks, TM=8 rows each
    dim3 block(256);
    hipLaunchKernelGGL(fused_dnn, grid, block, 0, stream,
                       emb, W1, b1, W2, b2, x, len, out);
}